// Round 7
// baseline (1215.991 us; speedup 1.0000x reference)
//
#include <hip/hip_runtime.h>
#include <stdint.h>

typedef unsigned long long u64;

static __device__ __forceinline__ int uread(int v) { return __builtin_amdgcn_readfirstlane(v); }
// force fp32 materialization (blocks fma-contraction / reassociation across steps)
static __device__ __forceinline__ float fr(float x) { __asm__ volatile("" : "+v"(x)); return x; }

// bn sign with numpy-faithful fp32 elementwise rounding:
// inv = 1/sqrt(v+1e-5f); si = g*inv; t1 = x-m; t2 = t1*si; bn = t2+b; return bn < 0
static __device__ __forceinline__ bool bn_neg(float x, float g, float b, float m, float v) {
    float inv = fr(1.0f / fr(sqrtf(fr(v + 1e-5f))));
    float si  = fr(g * inv);
    float t1  = fr(x - m);
    float t2  = fr(t1 * si);
    float bn  = fr(t2 + b);
    return bn < 0.0f;
}

// ---------------- weight pack kernels (sign: x>=0 -> +1; bit=1 means -1) ----------------

__global__ __launch_bounds__(256) void packw1_kernel(const float* __restrict__ w, float* __restrict__ ws) {
    int id = blockIdx.x * 256 + threadIdx.x;
    if (id >= 27 * 128) return;
    int co = id & 127, j = id >> 7;
    ws[j * 128 + co] = (w[co * 27 + j] < 0.f) ? -1.f : 1.f;
}

__global__ __launch_bounds__(256) void packw_conv_kernel(const float* __restrict__ w, u64* __restrict__ wb,
                                                         int CINW, int COUT) {
    int id = blockIdx.x * 256 + threadIdx.x;
    int total = 9 * CINW * COUT;
    if (id >= total) return;
    int co = id % COUT;
    int rest = id / COUT;
    int wrd = rest % CINW;
    int tap = rest / CINW;
    int CIN = CINW * 64;
    u64 bits = 0;
    const float* p = w + (size_t)(co * CIN + wrd * 64) * 9 + tap;
    for (int b = 0; b < 64; ++b)
        if (p[b * 9] < 0.f) bits |= (1ull << b);
    wb[(size_t)(tap * CINW + wrd) * COUT + co] = bits;
}

__global__ __launch_bounds__(256) void packw7_kernel(const float* __restrict__ w, u64* __restrict__ wb) {
    int id = blockIdx.x * 256 + threadIdx.x;
    if (id >= 1024 * 128) return;
    int k = id & 127, o = id >> 7;
    int pixel = k >> 3, cw = k & 7;
    u64 bits = 0;
    const float* p = w + (size_t)o * 8192 + (size_t)(cw * 64) * 16 + pixel;
    for (int b = 0; b < 64; ++b)
        if (p[b * 16] < 0.f) bits |= (1ull << b);
    wb[(size_t)k * 1024 + o] = bits;
}

__global__ __launch_bounds__(256) void packw8_kernel(const float* __restrict__ w, u64* __restrict__ wb) {
    int id = blockIdx.x * 256 + threadIdx.x;
    if (id >= 1024 * 16) return;
    int k = id & 15, o = id >> 4;
    u64 bits = 0;
    const float* p = w + (size_t)o * 1024 + k * 64;
    for (int b = 0; b < 64; ++b)
        if (p[b] < 0.f) bits |= (1ull << b);
    wb[(size_t)k * 1024 + o] = bits;
}

__global__ __launch_bounds__(256) void packw9_kernel(const float* __restrict__ w, u64* __restrict__ wb) {
    int id = blockIdx.x * 256 + threadIdx.x;
    if (id >= 160) return;
    int k = id & 15, o = id >> 4;
    u64 bits = 0;
    const float* p = w + (size_t)o * 1024 + k * 64;
    for (int b = 0; b < 64; ++b)
        if (p[b] < 0.f) bits |= (1ull << b);
    wb[k * 16 + o] = bits;
}

// ---------------- conv1: fp32, Eigen/XLA-CPU accumulation order ----------------
// XLA:CPU conv = NHWC Eigen spatial conv = im2col patches [.., KH, KW, C] (C fastest)
// contracted with ascending k into a single accumulator via FMA:
//   for ky: for kx: for ci: acc = fma(w, x, acc)      (padded taps = exact no-ops)
// x (N,3,32,32) fp32, w1s [j=ci*9+ky*3+kx][128] (+-1), out bits [n][32][32][2]
__global__ __launch_bounds__(256) void conv1_kernel(
    const float* __restrict__ x, const float* __restrict__ w1s,
    const float* __restrict__ g, const float* __restrict__ bb,
    const float* __restrict__ m, const float* __restrict__ v,
    u64* __restrict__ out, int N)
{
    int lane = threadIdx.x & 63;
    int rid = uread(blockIdx.x * 4 + (threadIdx.x >> 6));   // N*32 rows = n*32 + y
    if (rid >= N * 32) return;
    int n = rid >> 5, y = rid & 31;
    const float* xb = x + (size_t)n * 3072;
    for (int half = 0; half < 2; ++half) {
        int co = half * 64 + lane;
        float w[27];
#pragma unroll
        for (int j = 0; j < 27; ++j) w[j] = w1s[j * 128 + co];
        float gc = g[co], bc = bb[co], mc = m[co], vc = v[co];
        for (int xx = 0; xx < 32; ++xx) {
            float acc = 0.f;
            // strict (ky, kx, ci) order — ci innermost — serial fmaf chain
            for (int ky = 0; ky < 3; ++ky) {
                int yy = y + ky - 1;
                if (yy < 0 || yy >= 32) continue;
                for (int kx = 0; kx < 3; ++kx) {
                    int xs = xx + kx - 1;
                    if (xs < 0 || xs >= 32) continue;
                    for (int ci = 0; ci < 3; ++ci)
                        acc = fmaf(w[ci * 9 + ky * 3 + kx], xb[ci * 1024 + yy * 32 + xs], acc);
                }
            }
            u64 bits = __ballot(bn_neg(acc, gc, bc, mc, vc));
            if (lane == 0) out[(((size_t)n * 32 + y) * 32 + xx) * 2 + half] = bits;
        }
    }
}

// ---------------- binary conv (XNOR-popcount), fp32 bit-exact epilogue ----------------
// (binary dots are exact integers in fp32 in ANY order -> only the epilogue rounding matters)
// a: [n][H][W][WORDS] bits; wb: [tap*WORDS+w][COW*64]; out: [n][OH][OW][COW] bits
template<int WORDS, int COW, bool POOL, bool HAS_BIAS, int H, int W>
__global__ __launch_bounds__(256) void binconv_kernel(
    const u64* __restrict__ a, const u64* __restrict__ wb,
    const float* __restrict__ g, const float* __restrict__ bb,
    const float* __restrict__ m, const float* __restrict__ v,
    const float* __restrict__ bias, u64* __restrict__ out, int N)
{
    const int OH = POOL ? H / 2 : H, OW = POOL ? W / 2 : W;
    const int COUT = COW * 64;
    int lane = threadIdx.x & 63;
    int wid = uread(blockIdx.x * 4 + (threadIdx.x >> 6));
    if (wid >= N * OH * OW * COW) return;
    int cw = wid & (COW - 1); int tmp = wid / COW;
    int xo = tmp & (OW - 1); tmp /= OW;
    int yo = tmp & (OH - 1); int n = tmp / OH;
    int co = cw * 64 + lane;

    int best = -1000000;
#pragma unroll
    for (int sp = 0; sp < (POOL ? 4 : 1); ++sp) {
        int y = POOL ? yo * 2 + (sp >> 1) : yo;
        int x = POOL ? xo * 2 + (sp & 1) : xo;
        int acc = 0, nb = 0;
        for (int ky = 0; ky < 3; ++ky) {
            int yy = y + ky - 1;
            if (yy < 0 || yy >= H) continue;
            for (int kx = 0; kx < 3; ++kx) {
                int xx = x + kx - 1;
                if (xx < 0 || xx >= W) continue;
                const u64* ap = a + (size_t)((n * H + yy) * W + xx) * WORDS;
                const u64* wp = wb + (size_t)((ky * 3 + kx) * WORDS) * COUT + co;
#pragma unroll
                for (int w = 0; w < WORDS; ++w)
                    acc += __popcll(ap[w] ^ wp[(size_t)w * COUT]);
                nb += WORDS * 64;
            }
        }
        int dot = nb - 2 * acc;   // exact integer == golden's fp32 conv value
        best = (sp == 0) ? dot : max(best, dot);
    }
    // fl monotone => max commutes with the (dot+bias) rounding; bias constant per channel.
    float t = (float)best;                       // exact (|dot| < 2^24)
    if (HAS_BIAS) t = fr(t + bias[co]);          // one fp32 rounding, as golden
    u64 bits = __ballot(bn_neg(t, g[co], bb[co], m[co], v[co]));
    if (lane == 0) out[(size_t)((n * OH + yo) * OW + xo) * COW + cw] = bits;
}

// ---------------- binary FC, fp32 bit-exact epilogue ----------------
template<int KW, int OWRD>
__global__ __launch_bounds__(256) void binfc_kernel(
    const u64* __restrict__ a, const u64* __restrict__ wb,
    const float* __restrict__ g, const float* __restrict__ bb,
    const float* __restrict__ m, const float* __restrict__ v,
    u64* __restrict__ out, int N)
{
    int lane = threadIdx.x & 63;
    int wid = uread(blockIdx.x * 4 + (threadIdx.x >> 6));
    if (wid >= N * OWRD) return;
    int ow = wid & (OWRD - 1), n = wid / OWRD;
    int o = ow * 64 + lane;
    const u64* ap = a + (size_t)n * KW;
    int acc = 0;
#pragma unroll 8
    for (int k = 0; k < KW; ++k)
        acc += __popcll(ap[k] ^ wb[(size_t)k * (OWRD * 64) + o]);
    float dotf = (float)(KW * 64 - 2 * acc);
    u64 bits = __ballot(bn_neg(dotf, g[o], bb[o], m[o], v[o]));
    if (lane == 0) out[(size_t)n * OWRD + ow] = bits;
}

// ---------------- fc9 + bn(affine=False) + log_softmax, fp32 output ----------------
__global__ __launch_bounds__(64) void fc9_kernel(
    const u64* __restrict__ a, const u64* __restrict__ wb,
    const float* __restrict__ m, const float* __restrict__ v, float* __restrict__ out)
{
    int n = blockIdx.x, t = threadIdx.x;
    const u64* ap = a + (size_t)n * 16;
    float val = -1e30f;
    if (t < 10) {
        int acc = 0;
#pragma unroll
        for (int k = 0; k < 16; ++k) acc += __popcll(ap[k] ^ wb[k * 16 + t]);
        float dotf = (float)(1024 - 2 * acc);
        float inv = fr(1.0f / fr(sqrtf(fr(v[t] + 1e-5f))));
        float t1  = fr(dotf - m[t]);
        val = fr(t1 * inv);
    }
    float mx = val;
#pragma unroll
    for (int off = 32; off; off >>= 1) mx = fmaxf(mx, __shfl_xor(mx, off));
    float sh = fr(val - mx);                      // fp32 subtraction as golden
    double e = (t < 10) ? exp((double)sh) : 0.0;  // tail in fp64 (error << 4.34 threshold)
    double sum = e;
#pragma unroll
    for (int off = 32; off; off >>= 1) sum += __shfl_xor(sum, off);
    if (t < 10) out[n * 10 + t] = (float)((double)sh - log(sum));
}

extern "C" void kernel_launch(void* const* d_in, const int* in_sizes, int n_in,
                              void* d_out, int out_size, void* d_ws, size_t ws_size,
                              hipStream_t stream) {
    // setup_inputs() dict order (confirmed by in_sizes sniff in R5)
    auto F = [&](int i) { return (const float*)d_in[i]; };
    const float* x  = F(0);
    const float* w1 = F(1);  const float* g1 = F(2);  const float* b1 = F(3);
    const float* m1 = F(4);  const float* v1 = F(5);
    const float* w2 = F(6);  const float* g2 = F(7);  const float* b2 = F(8);
    const float* m2 = F(9);  const float* v2 = F(10);
    const float* w3 = F(11); const float* g3 = F(12); const float* b3 = F(13);
    const float* m3 = F(14); const float* v3 = F(15);
    const float* w4 = F(16); const float* g4 = F(17); const float* b4 = F(18);
    const float* m4 = F(19); const float* v4 = F(20);
    const float* w5 = F(21); const float* g5 = F(22); const float* b5 = F(23);
    const float* m5 = F(24); const float* v5 = F(25);
    const float* w6 = F(26); const float* g6 = F(27); const float* b6 = F(28);
    const float* m6 = F(29); const float* v6 = F(30);
    const float* bias2 = F(31);
    const float* w7 = F(32); const float* m7 = F(33); const float* v7 = F(34);
    const float* g7 = F(35); const float* b7 = F(36);
    const float* w8 = F(37); const float* m8 = F(38); const float* v8 = F(39);
    const float* g8 = F(40); const float* b8 = F(41);
    const float* w9 = F(42); const float* m9 = F(43); const float* v9 = F(44);
    (void)in_sizes; (void)n_in; (void)ws_size;

    const int N = out_size / 10;
    u64* ws = (u64*)d_ws;
    size_t off = 0;
    auto carve = [&](size_t nwords) { u64* p = ws + off; off += nwords; return p; };
    float* w1s = (float*)carve(1728);
    u64* w2p = carve(2304);
    u64* w3p = carve(4608);
    u64* w4p = carve(9216);
    u64* w5p = carve(18432);
    u64* w6p = carve(36864);
    u64* w7p = carve(131072);
    u64* w8p = carve(16384);
    u64* w9p = carve(256);
    u64* a1 = carve((size_t)N * 32 * 32 * 2);
    u64* a2 = carve((size_t)N * 16 * 16 * 2);
    u64* a3 = carve((size_t)N * 16 * 16 * 4);
    u64* a4 = carve((size_t)N * 8 * 8 * 4);
    u64* a5 = carve((size_t)N * 8 * 8 * 8);
    u64* a6 = carve((size_t)N * 16 * 8);
    u64* f7 = carve((size_t)N * 16);
    u64* f8 = carve((size_t)N * 16);

    packw1_kernel<<<(3456 + 255) / 256, 256, 0, stream>>>(w1, w1s);
    packw_conv_kernel<<<(2304 + 255) / 256, 256, 0, stream>>>(w2, w2p, 2, 128);
    packw_conv_kernel<<<(4608 + 255) / 256, 256, 0, stream>>>(w3, w3p, 2, 256);
    packw_conv_kernel<<<(9216 + 255) / 256, 256, 0, stream>>>(w4, w4p, 4, 256);
    packw_conv_kernel<<<(18432 + 255) / 256, 256, 0, stream>>>(w5, w5p, 4, 512);
    packw_conv_kernel<<<(36864 + 255) / 256, 256, 0, stream>>>(w6, w6p, 8, 512);
    packw7_kernel<<<(131072 + 255) / 256, 256, 0, stream>>>(w7, w7p);
    packw8_kernel<<<(16384 + 255) / 256, 256, 0, stream>>>(w8, w8p);
    packw9_kernel<<<1, 256, 0, stream>>>(w9, w9p);

    conv1_kernel<<<(N * 32 + 3) / 4, 256, 0, stream>>>(x, w1s, g1, b1, m1, v1, a1, N);

    binconv_kernel<2, 2, true, true, 32, 32><<<(N * 16 * 16 * 2 + 3) / 4, 256, 0, stream>>>(
        a1, w2p, g2, b2, m2, v2, bias2, a2, N);
    binconv_kernel<2, 4, false, false, 16, 16><<<(N * 16 * 16 * 4 + 3) / 4, 256, 0, stream>>>(
        a2, w3p, g3, b3, m3, v3, nullptr, a3, N);
    binconv_kernel<4, 4, true, false, 16, 16><<<(N * 8 * 8 * 4 + 3) / 4, 256, 0, stream>>>(
        a3, w4p, g4, b4, m4, v4, nullptr, a4, N);
    binconv_kernel<4, 8, false, false, 8, 8><<<(N * 8 * 8 * 8 + 3) / 4, 256, 0, stream>>>(
        a4, w5p, g5, b5, m5, v5, nullptr, a5, N);
    binconv_kernel<8, 8, true, false, 8, 8><<<(N * 4 * 4 * 8 + 3) / 4, 256, 0, stream>>>(
        a5, w6p, g6, b6, m6, v6, nullptr, a6, N);

    binfc_kernel<128, 16><<<(N * 16 + 3) / 4, 256, 0, stream>>>(a6, w7p, g7, b7, m7, v7, f7, N);
    binfc_kernel<16, 16><<<(N * 16 + 3) / 4, 256, 0, stream>>>(f7, w8p, g8, b8, m8, v8, f8, N);

    fc9_kernel<<<N, 64, 0, stream>>>(f8, w9p, m9, v9, (float*)d_out);
}